// Round 10
// baseline (119.472 us; speedup 1.0000x reference)
//
#include <hip/hip_runtime.h>
#include <math.h>

#define B_SZ 16
#define K_PTS 4096
#define ALPHA 1.1f
#define NB 256
#define BIGF 3.0e38f
#define EPSZ 1e-3f

// ws layout (bytes): pts4 float4[B][4096] @0 (1 MiB);
// perm uint[B][4096] @1048576; binb uint[B][4096] @1310720;
// hdr float[B][4] @1572864. total 1573120 B.
#define WS_PERM_OFF 1048576
#define WS_BINB_OFF 1310720
#define WS_HDR_OFF  1572864
#define WS_NEEDED   1573120

__device__ __forceinline__ void insert2(float d, float& m0, float& m1) {
    m1 = __builtin_amdgcn_fmed3f(d, m0, m1);
    m0 = fminf(d, m0);
}
__device__ __forceinline__ void insert3(float d, float& m0, float& m1, float& m2) {
    m2 = __builtin_amdgcn_fmed3f(d, m1, m2);
    m1 = __builtin_amdgcn_fmed3f(d, m0, m1);
    m0 = fminf(d, m0);
}

// Setup: per batch, counting-sort points into NB linear z-bins.
// Coalesced float4 staging of x into LDS; single-wave shfl prefix scan.
// Within-bin scatter order is nondeterministic (atomics) but downstream
// results are order-independent exact min-set selections.
__global__ __launch_bounds__(1024) void sor_setup(
    const float* __restrict__ x, float4* __restrict__ pts4,
    unsigned* __restrict__ perm, unsigned* __restrict__ binb,
    float* __restrict__ hdr)
{
    __shared__ float xs[K_PTS * 3];          // 48 KiB staged input
    __shared__ unsigned hist[NB];
    __shared__ unsigned scn[NB];
    __shared__ unsigned cur[NB];
    __shared__ float redmin[16], redmax[16];
    __shared__ float sh_zmin, sh_invw;

    const int b = blockIdx.x;
    const int tid = threadIdx.x;
    const float4* xb4 = (const float4*)(x + (size_t)b * K_PTS * 3);

    #pragma unroll
    for (int it = 0; it < 3; ++it)
        ((float4*)xs)[tid + it * 1024] = xb4[tid + it * 1024];
    if (tid < NB) hist[tid] = 0;
    __syncthreads();

    float z[4];
    float zmn = BIGF, zmx = -BIGF;
    #pragma unroll
    for (int k = 0; k < 4; ++k) {
        z[k] = xs[(tid + k * 1024) * 3 + 2];
        zmn = fminf(zmn, z[k]);
        zmx = fmaxf(zmx, z[k]);
    }
    #pragma unroll
    for (int off = 32; off > 0; off >>= 1) {
        zmn = fminf(zmn, __shfl_down(zmn, off, 64));
        zmx = fmaxf(zmx, __shfl_down(zmx, off, 64));
    }
    if ((tid & 63) == 0) { redmin[tid >> 6] = zmn; redmax[tid >> 6] = zmx; }
    __syncthreads();
    if (tid == 0) {
        float mn = redmin[0], mx = redmax[0];
        for (int wv = 1; wv < 16; ++wv) {
            mn = fminf(mn, redmin[wv]);
            mx = fmaxf(mx, redmax[wv]);
        }
        const float rng = fmaxf(mx - mn, 1e-6f);
        const float w = rng * (1.0f / NB);
        sh_zmin = mn;
        sh_invw = 1.0f / w;
        hdr[b * 4 + 0] = mn;
        hdr[b * 4 + 1] = w;
        hdr[b * 4 + 2] = 1.0f / w;
    }
    __syncthreads();
    const float zmin = sh_zmin, invw = sh_invw;

    int kb[4];
    #pragma unroll
    for (int k = 0; k < 4; ++k) {
        int kk = (int)((z[k] - zmin) * invw);
        kk = min(NB - 1, max(0, kk));
        kb[k] = kk;
        atomicAdd(&hist[kk], 1u);
    }
    if (tid < NB) cur[tid] = 0;
    __syncthreads();

    // inclusive scan of hist by wave 0 (4 bins/lane + shfl_up scan)
    if (tid < 64) {
        const unsigned h0 = hist[tid * 4 + 0];
        const unsigned h1 = hist[tid * 4 + 1];
        const unsigned h2 = hist[tid * 4 + 2];
        const unsigned h3 = hist[tid * 4 + 3];
        const unsigned p0 = h0, p1 = p0 + h1, p2 = p1 + h2, p3 = p2 + h3;
        unsigned t = p3;
        #pragma unroll
        for (int off = 1; off < 64; off <<= 1) {
            const unsigned u = __shfl_up(t, off, 64);
            if (tid >= off) t += u;
        }
        const unsigned base = t - p3;     // exclusive prefix of lane totals
        scn[tid * 4 + 0] = base + p0;
        scn[tid * 4 + 1] = base + p1;
        scn[tid * 4 + 2] = base + p2;
        scn[tid * 4 + 3] = base + p3;
    }
    __syncthreads();

    #pragma unroll
    for (int k = 0; k < 4; ++k) {
        const int p = tid + k * 1024;
        const int kk = kb[k];
        const unsigned pos = (scn[kk] - hist[kk]) + atomicAdd(&cur[kk], 1u);
        const float a0 = xs[p * 3 + 0];
        const float a1 = xs[p * 3 + 1];
        const float a2 = z[k];
        pts4[(size_t)b * K_PTS + pos] = make_float4(a0, a1, a2, a0 * a0 + a1 * a1 + a2 * a2);
        perm[(size_t)b * K_PTS + pos] = (unsigned)p;
        binb[(size_t)b * K_PTS + pos] = (unsigned)kk;
    }
}

// Exact pruned 2NN search. grid (16 s, 16 b) x 256 thr (4 waves).
// Wave w handles z-group g0 = s + w*16 (strided -> per-block work ~= batch
// average). Lane owns point i = g0*64+lane. Top-3 incl self over an outward
// two-sided group scan; release when bin-edge gap^2 > m2 + wi (conservative-
// exact, EPSZ absorbs binning fp slack). Candidates are consumed in PAIRS:
// half-waves read pts[j] / pts[j+1] (one conflict-free ds_read_b128 per 2
// candidates), then v_permlane32_swap_b32 (VALU pipe) makes both points
// wave-uniform. With a==b==P pre-swap, ANY half-exchange semantic yields
// {pt[j] uniform, pt[j+1] uniform} in some order - order is irrelevant for
// min-set selection.
#define PAIR(JB) { \
    const float4 P = pts[(JB) + hsel]; \
    float ax = P.x, bx = P.x, ay = P.y, by = P.y; \
    float az = P.z, bz = P.z, aw = P.w, bw = P.w; \
    asm("v_permlane32_swap_b32 %0, %1" : "+v"(ax), "+v"(bx)); \
    asm("v_permlane32_swap_b32 %0, %1" : "+v"(ay), "+v"(by)); \
    asm("v_permlane32_swap_b32 %0, %1" : "+v"(az), "+v"(bz)); \
    asm("v_permlane32_swap_b32 %0, %1" : "+v"(aw), "+v"(bw)); \
    float tA = fmaf(kz, az, aw); tA = fmaf(ky, ay, tA); \
    const float dA = fmaf(kx, ax, tA); \
    insert3(dA, m0, m1, m2); \
    float tB = fmaf(kz, bz, bw); tB = fmaf(ky, by, tB); \
    const float dB = fmaf(kx, bx, tB); \
    insert3(dB, m0, m1, m2); \
}

#define GROUP(G) { const int jb0 = (G) * 64; \
    _Pragma("unroll 8") for (int jj = 0; jj < 32; ++jj) { PAIR(jb0 + jj * 2) } }

__global__ __launch_bounds__(256) void sor_search(
    const float4* __restrict__ pts4, const unsigned* __restrict__ perm,
    const unsigned* __restrict__ binb, const float* __restrict__ hdr,
    float* __restrict__ value)
{
    __shared__ float4 pts[K_PTS];      // 64 KiB
    __shared__ float zfl[64], zcl[64];

    const int b = blockIdx.y;
    const int s = blockIdx.x;
    const int tid = threadIdx.x;

    const float zmin = hdr[b * 4 + 0];
    const float w    = hdr[b * 4 + 1];

    #pragma unroll
    for (int it = 0; it < 16; ++it) {
        const int idx = tid + it * 256;
        pts[idx] = pts4[(size_t)b * K_PTS + idx];
    }
    if (tid < 64) {
        // all points at position >= g*64 have z >= zfl[g];
        // all points at position <= g*64+63 have z <= zcl[g].
        zfl[tid] = zmin + (float)binb[(size_t)b * K_PTS + tid * 64] * w;
        zcl[tid] = zmin + (float)(binb[(size_t)b * K_PTS + tid * 64 + 63] + 1u) * w;
    }
    __syncthreads();

    const int lane = tid & 63;
    const int wv = tid >> 6;
    const int g0 = s + wv * 16;        // strided group assignment
    const int i = g0 * 64 + lane;
    const int hsel = lane >> 5;        // 0 for lanes 0-31, 1 for lanes 32-63

    const float4 q = pts[i];
    const float wi = q.w, zi = q.z;
    const float kx = -2.0f * q.x, ky = -2.0f * q.y, kz = -2.0f * q.z;

    float m0 = BIGF, m1 = BIGF, m2 = BIGF;

    GROUP(g0)                          // own group (self included; m0 = self)

    int gu = g0 + 1, gd = g0 - 1;
    bool upa = (gu < 64), dna = (gd >= 0);
    while (upa || dna) {
        if (upa) {
            const float gap = fmaxf(zfl[gu] - zi - EPSZ, 0.0f);
            const bool act = (gap * gap <= m2 + wi);
            if (__ballot(act) == 0ull) upa = false;
            else { GROUP(gu) ++gu; upa = (gu < 64); }
        }
        if (dna) {
            const float gap = fmaxf(zi - zcl[gd] - EPSZ, 0.0f);
            const bool act = (gap * gap <= m2 + wi);
            if (__ballot(act) == 0ull) dna = false;
            else { GROUP(gd) --gd; dna = (gd >= 0); }
        }
    }

    // self (= m0, strict min) dropped; 2NN = (m1, m2)
    const unsigned orig = perm[(size_t)b * K_PTS + i];
    value[(size_t)b * K_PTS + orig] = ((m1 + wi) + (m2 + wi)) * 0.5f;
}

// One block per batch: mean/std(ddof=1) -> threshold -> mask + zeroed points.
__global__ __launch_bounds__(1024) void sor_mask_kernel(
    const float* __restrict__ x, float* __restrict__ out)
{
    const int b = blockIdx.x;
    const int tid = threadIdx.x;
    float* value = out + (size_t)B_SZ * K_PTS * 3;
    float* selpc = out;

    __shared__ float red[16];
    __shared__ float sh_mean, sh_thr;

    float v[4];
    float sm = 0.0f;
    #pragma unroll
    for (int k = 0; k < 4; ++k) {
        v[k] = value[b * K_PTS + tid + k * 1024];
        sm += v[k];
    }
    #pragma unroll
    for (int off = 32; off > 0; off >>= 1) sm += __shfl_down(sm, off, 64);
    if ((tid & 63) == 0) red[tid >> 6] = sm;
    __syncthreads();
    if (tid == 0) {
        float t = 0.0f;
        for (int wv = 0; wv < 16; ++wv) t += red[wv];
        sh_mean = t * (1.0f / (float)K_PTS);
    }
    __syncthreads();
    const float mean = sh_mean;

    float qv = 0.0f;
    #pragma unroll
    for (int k = 0; k < 4; ++k) { float dv = v[k] - mean; qv += dv * dv; }
    #pragma unroll
    for (int off = 32; off > 0; off >>= 1) qv += __shfl_down(qv, off, 64);
    if ((tid & 63) == 0) red[tid >> 6] = qv;
    __syncthreads();
    if (tid == 0) {
        float t = 0.0f;
        for (int wv = 0; wv < 16; ++wv) t += red[wv];
        sh_thr = mean + ALPHA * sqrtf(t / (float)(K_PTS - 1));
    }
    __syncthreads();
    const float thr = sh_thr;

    #pragma unroll
    for (int k = 0; k < 4; ++k) {
        const int i = tid + k * 1024;
        const bool keep = v[k] <= thr;
        value[b * K_PTS + i] = keep ? 1.0f : 0.0f;
        const size_t base = ((size_t)b * K_PTS + i) * 3;
        float x0 = x[base + 0];
        float x1 = x[base + 1];
        float x2 = x[base + 2];
        selpc[base + 0] = keep ? x0 : 0.0f;
        selpc[base + 1] = keep ? x1 : 0.0f;
        selpc[base + 2] = keep ? x2 : 0.0f;
    }
}

// ---- Fallback (round-1 structure) used only if d_ws is too small ----
__global__ __launch_bounds__(256) void sor_value_kernel(
    const float* __restrict__ x, float* __restrict__ value)
{
    __shared__ float4 pts[K_PTS];
    const int b = blockIdx.y;
    const float* xb = x + (size_t)b * K_PTS * 3;
    for (int p = threadIdx.x; p < K_PTS; p += 256) {
        float a0 = xb[p * 3 + 0];
        float a1 = xb[p * 3 + 1];
        float a2 = xb[p * 3 + 2];
        pts[p] = make_float4(a0, a1, a2, a0 * a0 + a1 * a1 + a2 * a2);
    }
    __syncthreads();
    const int i = blockIdx.x * 256 + threadIdx.x;
    const float4 pi = pts[i];
    float m0 = BIGF, m1 = BIGF, m2 = BIGF;
    #pragma unroll 8
    for (int j = 0; j < K_PTS; ++j) {
        float4 pj = pts[j];
        float dot = pi.x * pj.x + pi.y * pj.y + pi.z * pj.z;
        float d = (pi.w - 2.0f * dot) + pj.w;
        insert3(d, m0, m1, m2);
    }
    value[b * K_PTS + i] = 0.5f * (m1 + m2);
}

extern "C" void kernel_launch(void* const* d_in, const int* in_sizes, int n_in,
                              void* d_out, int out_size, void* d_ws, size_t ws_size,
                              hipStream_t stream)
{
    const float* x = (const float*)d_in[0];
    float* out = (float*)d_out;
    float* value = out + (size_t)B_SZ * K_PTS * 3;

    if (ws_size >= (size_t)WS_NEEDED) {
        float4* pts4 = (float4*)d_ws;
        unsigned* perm = (unsigned*)((char*)d_ws + WS_PERM_OFF);
        unsigned* binb = (unsigned*)((char*)d_ws + WS_BINB_OFF);
        float* hdr = (float*)((char*)d_ws + WS_HDR_OFF);

        sor_setup<<<B_SZ, 1024, 0, stream>>>(x, pts4, perm, binb, hdr);
        dim3 gS(16, B_SZ);   // (16,16) = 256 blocks, one per CU
        sor_search<<<gS, 256, 0, stream>>>(pts4, perm, binb, hdr, value);
    } else {
        dim3 g1(K_PTS / 256, B_SZ);
        sor_value_kernel<<<g1, 256, 0, stream>>>(x, value);
    }
    sor_mask_kernel<<<B_SZ, 1024, 0, stream>>>(x, out);
}

// Round 11
// 82.364 us; speedup vs baseline: 1.4505x; 1.4505x over previous
//
#include <hip/hip_runtime.h>
#include <math.h>

#define B_SZ 16
#define K_PTS 4096
#define ALPHA 1.1f
#define NB 256
#define BIGF 3.0e38f

// ws layout (bytes): pts4 float4[B][4096] @0 (1 MiB);
// perm uint[B][4096] @1048576; (gap); hdr float[B][4] @1572864.
#define WS_PERM_OFF 1048576
#define WS_HDR_OFF  1572864
#define WS_NEEDED   1573120

__device__ __forceinline__ void insert2(float d, float& m0, float& m1) {
    m1 = __builtin_amdgcn_fmed3f(d, m0, m1);
    m0 = fminf(d, m0);
}
__device__ __forceinline__ void insert3(float d, float& m0, float& m1, float& m2) {
    m2 = __builtin_amdgcn_fmed3f(d, m1, m2);
    m1 = __builtin_amdgcn_fmed3f(d, m0, m1);
    m0 = fminf(d, m0);
}

// Setup: per batch, counting-sort points into NB linear z-bins (sorted across
// bins, arbitrary within bin - downstream uses a one-bin-width slack).
__global__ __launch_bounds__(1024) void sor_setup(
    const float* __restrict__ x, float4* __restrict__ pts4,
    unsigned* __restrict__ perm, float* __restrict__ hdr)
{
    __shared__ float xs[K_PTS * 3];          // 48 KiB staged input
    __shared__ unsigned hist[NB];
    __shared__ unsigned scn[NB];
    __shared__ unsigned cur[NB];
    __shared__ float redmin[16], redmax[16];
    __shared__ float sh_zmin, sh_invw;

    const int b = blockIdx.x;
    const int tid = threadIdx.x;
    const float4* xb4 = (const float4*)(x + (size_t)b * K_PTS * 3);

    #pragma unroll
    for (int it = 0; it < 3; ++it)
        ((float4*)xs)[tid + it * 1024] = xb4[tid + it * 1024];
    if (tid < NB) hist[tid] = 0;
    __syncthreads();

    float z[4];
    float zmn = BIGF, zmx = -BIGF;
    #pragma unroll
    for (int k = 0; k < 4; ++k) {
        z[k] = xs[(tid + k * 1024) * 3 + 2];
        zmn = fminf(zmn, z[k]);
        zmx = fmaxf(zmx, z[k]);
    }
    #pragma unroll
    for (int off = 32; off > 0; off >>= 1) {
        zmn = fminf(zmn, __shfl_down(zmn, off, 64));
        zmx = fmaxf(zmx, __shfl_down(zmx, off, 64));
    }
    if ((tid & 63) == 0) { redmin[tid >> 6] = zmn; redmax[tid >> 6] = zmx; }
    __syncthreads();
    if (tid == 0) {
        float mn = redmin[0], mx = redmax[0];
        for (int wv = 1; wv < 16; ++wv) {
            mn = fminf(mn, redmin[wv]);
            mx = fmaxf(mx, redmax[wv]);
        }
        const float rng = fmaxf(mx - mn, 1e-6f);
        const float w = rng * (1.0f / NB);
        sh_zmin = mn;
        sh_invw = 1.0f / w;
        hdr[b * 4 + 0] = mn;
        hdr[b * 4 + 1] = w;
        hdr[b * 4 + 2] = 1.0f / w;
    }
    __syncthreads();
    const float zmin = sh_zmin, invw = sh_invw;

    int kb[4];
    #pragma unroll
    for (int k = 0; k < 4; ++k) {
        int kk = (int)((z[k] - zmin) * invw);
        kk = min(NB - 1, max(0, kk));
        kb[k] = kk;
        atomicAdd(&hist[kk], 1u);
    }
    if (tid < NB) cur[tid] = 0;
    __syncthreads();

    // inclusive scan of hist by wave 0 (4 bins/lane + shfl_up scan)
    if (tid < 64) {
        const unsigned h0 = hist[tid * 4 + 0];
        const unsigned h1 = hist[tid * 4 + 1];
        const unsigned h2 = hist[tid * 4 + 2];
        const unsigned h3 = hist[tid * 4 + 3];
        const unsigned p0 = h0, p1 = p0 + h1, p2 = p1 + h2, p3 = p2 + h3;
        unsigned t = p3;
        #pragma unroll
        for (int off = 1; off < 64; off <<= 1) {
            const unsigned u = __shfl_up(t, off, 64);
            if (tid >= off) t += u;
        }
        const unsigned base = t - p3;     // exclusive prefix of lane totals
        scn[tid * 4 + 0] = base + p0;
        scn[tid * 4 + 1] = base + p1;
        scn[tid * 4 + 2] = base + p2;
        scn[tid * 4 + 3] = base + p3;
    }
    __syncthreads();

    #pragma unroll
    for (int k = 0; k < 4; ++k) {
        const int p = tid + k * 1024;
        const int kk = kb[k];
        const unsigned pos = (scn[kk] - hist[kk]) + atomicAdd(&cur[kk], 1u);
        const float a0 = xs[p * 3 + 0];
        const float a1 = xs[p * 3 + 1];
        const float a2 = z[k];
        pts4[(size_t)b * K_PTS + pos] = make_float4(a0, a1, a2, a0 * a0 + a1 * a1 + a2 * a2);
        perm[(size_t)b * K_PTS + pos] = (unsigned)p;
    }
}

// Exact pruned 2NN search, per-lane gather scan. grid (16 s, 16 b) x 512 thr
// (8 waves). Waves 0-3 scan UP (j > i), waves 4-7 scan DOWN (j < i); wave wq
// owns group g0 = s + wq*16 (strided -> balanced), lane owns point
// i = g0*64+lane. Each lane walks its OWN window over the z-sorted array in
// unconditional 8-candidate chunks (8 per-lane ds_read_b128 at immediate
// offsets -> pipelined; gather serves 64 candidates per instruction).
// Release check once per chunk: remaining points have z >= z_read - delta
// (delta = bin width + eps covers within-bin disorder) -> stop when
// (gap-delta)^2 > m1 + wi. Overshoot inserts are real points -> always
// correct. Self excluded by construction. Sentinel padding (w=BIGF) makes
// out-of-range reads harmless; bounds release is explicit.
__global__ __launch_bounds__(512) void sor_search(
    const float4* __restrict__ pts4, const unsigned* __restrict__ perm,
    const float* __restrict__ hdr, float* __restrict__ value)
{
    __shared__ float4 buf[8 + K_PTS + 8];    // 64 KiB + 256 B pads
    __shared__ float2 dnres[256];
    float4* pts = buf + 8;

    const int b = blockIdx.y;
    const int s = blockIdx.x;
    const int tid = threadIdx.x;

    #pragma unroll
    for (int it = 0; it < 8; ++it) {
        const int idx = tid + it * 512;
        pts[idx] = pts4[(size_t)b * K_PTS + idx];
    }
    if (tid < 8) {
        buf[tid] = make_float4(0.0f, 0.0f, 0.0f, BIGF);
        buf[8 + K_PTS + tid] = make_float4(0.0f, 0.0f, 0.0f, BIGF);
    }
    __syncthreads();

    const float delta = hdr[b * 4 + 1] * 1.0001f + 1e-6f;

    const int lane = tid & 63;
    const int wv = tid >> 6;
    const int role = wv >> 2;          // 0 = up, 1 = down
    const int wq = wv & 3;
    const int g0 = s + wq * 16;        // strided group assignment
    const int i = g0 * 64 + lane;

    const float4 q = pts[i];
    const float wi = q.w, zi = q.z;
    const float kx = -2.0f * q.x, ky = -2.0f * q.y, kz = -2.0f * q.z;

    float m0 = BIGF, m1 = BIGF;

    if (role == 0) {
        int jb = i + 1;
        bool act = true;
        while (__ballot(act) != 0ull) {
            if (act) {
                float4 c[8];
                #pragma unroll
                for (int t = 0; t < 8; ++t) c[t] = pts[jb + t];
                #pragma unroll
                for (int t = 0; t < 8; ++t) {
                    float d = fmaf(kz, c[t].z, c[t].w);
                    d = fmaf(ky, c[t].y, d);
                    d = fmaf(kx, c[t].x, d);
                    insert2(d, m0, m1);
                }
                const float gap = fmaxf((c[7].z - zi) - delta, 0.0f);
                const bool done = (jb + 7 >= K_PTS - 1) || (gap * gap > m1 + wi);
                act = !done;
                jb += 8;
            }
        }
    } else {
        int jb = i - 1;
        bool act = true;
        while (__ballot(act) != 0ull) {
            if (act) {
                float4 c[8];
                #pragma unroll
                for (int t = 0; t < 8; ++t) c[t] = pts[jb - 7 + t];
                #pragma unroll
                for (int t = 0; t < 8; ++t) {
                    float d = fmaf(kz, c[t].z, c[t].w);
                    d = fmaf(ky, c[t].y, d);
                    d = fmaf(kx, c[t].x, d);
                    insert2(d, m0, m1);
                }
                const float gap = fmaxf((zi - c[0].z) - delta, 0.0f);
                const bool done = (jb <= 7) || (gap * gap > m1 + wi);
                act = !done;
                jb -= 8;
            }
        }
        dnres[wq * 64 + lane] = make_float2(m0, m1);
    }
    __syncthreads();

    if (role == 0) {
        const float2 dn = dnres[wq * 64 + lane];
        float M0 = BIGF, M1 = BIGF;
        insert2(m0, M0, M1);
        insert2(m1, M0, M1);
        insert2(dn.x, M0, M1);
        insert2(dn.y, M0, M1);
        const unsigned orig = perm[(size_t)b * K_PTS + i];
        value[(size_t)b * K_PTS + orig] = ((M0 + wi) + (M1 + wi)) * 0.5f;
    }
}

// One block per batch: mean/std(ddof=1) -> threshold -> mask + zeroed points.
__global__ __launch_bounds__(1024) void sor_mask_kernel(
    const float* __restrict__ x, float* __restrict__ out)
{
    const int b = blockIdx.x;
    const int tid = threadIdx.x;
    float* value = out + (size_t)B_SZ * K_PTS * 3;
    float* selpc = out;

    __shared__ float red[16];
    __shared__ float sh_mean, sh_thr;

    float v[4];
    float sm = 0.0f;
    #pragma unroll
    for (int k = 0; k < 4; ++k) {
        v[k] = value[b * K_PTS + tid + k * 1024];
        sm += v[k];
    }
    #pragma unroll
    for (int off = 32; off > 0; off >>= 1) sm += __shfl_down(sm, off, 64);
    if ((tid & 63) == 0) red[tid >> 6] = sm;
    __syncthreads();
    if (tid == 0) {
        float t = 0.0f;
        for (int wv = 0; wv < 16; ++wv) t += red[wv];
        sh_mean = t * (1.0f / (float)K_PTS);
    }
    __syncthreads();
    const float mean = sh_mean;

    float qv = 0.0f;
    #pragma unroll
    for (int k = 0; k < 4; ++k) { float dv = v[k] - mean; qv += dv * dv; }
    #pragma unroll
    for (int off = 32; off > 0; off >>= 1) qv += __shfl_down(qv, off, 64);
    if ((tid & 63) == 0) red[tid >> 6] = qv;
    __syncthreads();
    if (tid == 0) {
        float t = 0.0f;
        for (int wv = 0; wv < 16; ++wv) t += red[wv];
        sh_thr = mean + ALPHA * sqrtf(t / (float)(K_PTS - 1));
    }
    __syncthreads();
    const float thr = sh_thr;

    #pragma unroll
    for (int k = 0; k < 4; ++k) {
        const int i = tid + k * 1024;
        const bool keep = v[k] <= thr;
        value[b * K_PTS + i] = keep ? 1.0f : 0.0f;
        const size_t base = ((size_t)b * K_PTS + i) * 3;
        float x0 = x[base + 0];
        float x1 = x[base + 1];
        float x2 = x[base + 2];
        selpc[base + 0] = keep ? x0 : 0.0f;
        selpc[base + 1] = keep ? x1 : 0.0f;
        selpc[base + 2] = keep ? x2 : 0.0f;
    }
}

// ---- Fallback (round-1 structure) used only if d_ws is too small ----
__global__ __launch_bounds__(256) void sor_value_kernel(
    const float* __restrict__ x, float* __restrict__ value)
{
    __shared__ float4 pts[K_PTS];
    const int b = blockIdx.y;
    const float* xb = x + (size_t)b * K_PTS * 3;
    for (int p = threadIdx.x; p < K_PTS; p += 256) {
        float a0 = xb[p * 3 + 0];
        float a1 = xb[p * 3 + 1];
        float a2 = xb[p * 3 + 2];
        pts[p] = make_float4(a0, a1, a2, a0 * a0 + a1 * a1 + a2 * a2);
    }
    __syncthreads();
    const int i = blockIdx.x * 256 + threadIdx.x;
    const float4 pi = pts[i];
    float m0 = BIGF, m1 = BIGF, m2 = BIGF;
    #pragma unroll 8
    for (int j = 0; j < K_PTS; ++j) {
        float4 pj = pts[j];
        float dot = pi.x * pj.x + pi.y * pj.y + pi.z * pj.z;
        float d = (pi.w - 2.0f * dot) + pj.w;
        insert3(d, m0, m1, m2);
    }
    value[b * K_PTS + i] = 0.5f * (m1 + m2);
}

extern "C" void kernel_launch(void* const* d_in, const int* in_sizes, int n_in,
                              void* d_out, int out_size, void* d_ws, size_t ws_size,
                              hipStream_t stream)
{
    const float* x = (const float*)d_in[0];
    float* out = (float*)d_out;
    float* value = out + (size_t)B_SZ * K_PTS * 3;

    if (ws_size >= (size_t)WS_NEEDED) {
        float4* pts4 = (float4*)d_ws;
        unsigned* perm = (unsigned*)((char*)d_ws + WS_PERM_OFF);
        float* hdr = (float*)((char*)d_ws + WS_HDR_OFF);

        sor_setup<<<B_SZ, 1024, 0, stream>>>(x, pts4, perm, hdr);
        dim3 gS(16, B_SZ);   // (16,16) = 256 blocks, one per CU
        sor_search<<<gS, 512, 0, stream>>>(pts4, perm, hdr, value);
    } else {
        dim3 g1(K_PTS / 256, B_SZ);
        sor_value_kernel<<<g1, 256, 0, stream>>>(x, value);
    }
    sor_mask_kernel<<<B_SZ, 1024, 0, stream>>>(x, out);
}

// Round 12
// 45.347 us; speedup vs baseline: 2.6346x; 1.8163x over previous
//
#include <hip/hip_runtime.h>
#include <math.h>

#define B_SZ 16
#define K_PTS 4096
#define ALPHA 1.1f

#define JS 16                 // j-tiles per row
#define JTT (K_PTS / JS)      // 256 points per j-tile
#define ICH 1024              // i-points covered per block
#define THR 256

#define BIGF 3.0e38f

__device__ __forceinline__ void insert2(float d, float& m0, float& m1) {
    m1 = __builtin_amdgcn_fmed3f(d, m0, m1);
    m0 = fminf(d, m0);
}
__device__ __forceinline__ void insert3(float d, float& m0, float& m1, float& m2) {
    m2 = __builtin_amdgcn_fmed3f(d, m1, m2);
    m1 = __builtin_amdgcn_fmed3f(d, m0, m1);
    m0 = fminf(d, m0);
}

// Partial top-2 of shifted distance d' = -2<xi,xj> + ||xj||^2 over one j-tile.
// grid (64, B): bx = ic*16 + js. In diagonal blocks ((js>>2)==ic) the chain
// that owns the self-containing i-range is SWAPPED to chain 0, which keeps
// top-3 and drops m0 (= self, the strict tile min since d'_self = -||xi||^2
// is the unique row minimum). All other chains keep top-2 (5 VALU/pair).
// Load imbalance diag vs off-diag: 21 vs 20 VALU per j (~5%).
__global__ __launch_bounds__(256) void sor_partial2(
    const float* __restrict__ x, float* __restrict__ ws)
{
    __shared__ float4 pts[JTT];   // 4 KiB: (x, y, z, ||x||^2)
    const int b  = blockIdx.y;
    const int ic = blockIdx.x >> 4;
    const int js = blockIdx.x & 15;
    const int j0 = js * JTT;
    const float* xb = x + (size_t)b * K_PTS * 3;

    for (int p = threadIdx.x; p < JTT; p += THR) {
        float a0 = xb[(j0 + p) * 3 + 0];
        float a1 = xb[(j0 + p) * 3 + 1];
        float a2 = xb[(j0 + p) * 3 + 2];
        pts[p] = make_float4(a0, a1, a2, a0 * a0 + a1 * a1 + a2 * a2);
    }
    __syncthreads();

    const int ibase = ic * ICH + threadIdx.x;
    const bool diag = ((js >> 2) == ic);
    const int kstar = js & 3;

    // chain c -> point index idx[c]; in diag blocks swap chain 0 <-> kstar.
    int idx[4];
    #pragma unroll
    for (int c = 0; c < 4; ++c) idx[c] = ibase + c * THR;
    if (diag) { idx[0] = ibase + kstar * THR; idx[kstar] = ibase; }

    float x2[4], y2[4], z2[4], m0[4], m1[4];
    #pragma unroll
    for (int c = 0; c < 4; ++c) {
        const float* p = xb + (size_t)idx[c] * 3;
        x2[c] = -2.0f * p[0];
        y2[c] = -2.0f * p[1];
        z2[c] = -2.0f * p[2];
        m0[c] = BIGF; m1[c] = BIGF;
    }

    float* wbase = ws + (size_t)((b * JS + js) * 2) * K_PTS;

    if (diag) {
        float m2_0 = BIGF;
        #pragma unroll 8
        for (int j = 0; j < JTT; ++j) {
            const float4 pj = pts[j];
            {   // chain 0: contains self -> top-3
                float t = fmaf(z2[0], pj.z, pj.w);
                t = fmaf(y2[0], pj.y, t);
                float d = fmaf(x2[0], pj.x, t);
                insert3(d, m0[0], m1[0], m2_0);
            }
            #pragma unroll
            for (int c = 1; c < 4; ++c) {
                float t = fmaf(z2[c], pj.z, pj.w);
                t = fmaf(y2[c], pj.y, t);
                float d = fmaf(x2[c], pj.x, t);
                insert2(d, m0[c], m1[c]);
            }
        }
        // chain 0 drops m0 (self)
        wbase[idx[0]]         = m1[0];
        wbase[K_PTS + idx[0]] = m2_0;
        #pragma unroll
        for (int c = 1; c < 4; ++c) {
            wbase[idx[c]]         = m0[c];
            wbase[K_PTS + idx[c]] = m1[c];
        }
    } else {
        #pragma unroll 8
        for (int j = 0; j < JTT; ++j) {
            const float4 pj = pts[j];
            #pragma unroll
            for (int c = 0; c < 4; ++c) {
                float t = fmaf(z2[c], pj.z, pj.w);
                t = fmaf(y2[c], pj.y, t);
                float d = fmaf(x2[c], pj.x, t);
                insert2(d, m0[c], m1[c]);
            }
        }
        #pragma unroll
        for (int c = 0; c < 4; ++c) {
            wbase[idx[c]]         = m0[c];
            wbase[K_PTS + idx[c]] = m1[c];
        }
    }
}

// Merge 16 tiles x 2 candidates per point -> mean 2NN distance. 256 blocks.
__global__ __launch_bounds__(256) void sor_merge(
    const float* __restrict__ x, const float* __restrict__ ws,
    float* __restrict__ value)
{
    const int gid = blockIdx.x * 256 + threadIdx.x;   // 0 .. B*K-1
    const int b = gid >> 12;
    const int i = gid & (K_PTS - 1);

    float m0 = BIGF, m1 = BIGF;
    #pragma unroll
    for (int js = 0; js < JS; ++js) {
        const float* w = ws + (size_t)((b * JS + js) * 2) * K_PTS + i;
        insert2(w[0], m0, m1);
        insert2(w[K_PTS], m0, m1);
    }
    const float a0 = x[(size_t)gid * 3 + 0];
    const float a1 = x[(size_t)gid * 3 + 1];
    const float a2 = x[(size_t)gid * 3 + 2];
    const float xx = a0 * a0 + a1 * a1 + a2 * a2;
    // un-shift: true distances are m' + ||xi||^2; (m0,m1) = 2NN sorted.
    value[gid] = ((m0 + xx) + (m1 + xx)) * 0.5f;
}

// One block per batch: mean/std(ddof=1) -> threshold -> mask + zeroed points.
// Reads value from out's mask region, overwrites it with the 0/1 mask.
__global__ __launch_bounds__(1024) void sor_mask_kernel(
    const float* __restrict__ x, float* __restrict__ out)
{
    const int b = blockIdx.x;
    const int tid = threadIdx.x;
    float* value = out + (size_t)B_SZ * K_PTS * 3;
    float* selpc = out;

    __shared__ float red[16];
    __shared__ float sh_mean, sh_thr;

    float v[4];
    float s = 0.0f;
    #pragma unroll
    for (int k = 0; k < 4; ++k) {
        v[k] = value[b * K_PTS + tid + k * 1024];
        s += v[k];
    }
    #pragma unroll
    for (int off = 32; off > 0; off >>= 1) s += __shfl_down(s, off, 64);
    if ((tid & 63) == 0) red[tid >> 6] = s;
    __syncthreads();
    if (tid == 0) {
        float t = 0.0f;
        for (int w = 0; w < 16; ++w) t += red[w];
        sh_mean = t * (1.0f / (float)K_PTS);
    }
    __syncthreads();
    const float mean = sh_mean;

    float q = 0.0f;
    #pragma unroll
    for (int k = 0; k < 4; ++k) { float dv = v[k] - mean; q += dv * dv; }
    #pragma unroll
    for (int off = 32; off > 0; off >>= 1) q += __shfl_down(q, off, 64);
    if ((tid & 63) == 0) red[tid >> 6] = q;
    __syncthreads();
    if (tid == 0) {
        float t = 0.0f;
        for (int w = 0; w < 16; ++w) t += red[w];
        sh_thr = mean + ALPHA * sqrtf(t / (float)(K_PTS - 1));
    }
    __syncthreads();
    const float thr = sh_thr;

    #pragma unroll
    for (int k = 0; k < 4; ++k) {
        const int i = tid + k * 1024;
        const bool keep = v[k] <= thr;
        value[b * K_PTS + i] = keep ? 1.0f : 0.0f;
        const size_t base = ((size_t)b * K_PTS + i) * 3;
        float x0 = x[base + 0];
        float x1 = x[base + 1];
        float x2 = x[base + 2];
        selpc[base + 0] = keep ? x0 : 0.0f;
        selpc[base + 1] = keep ? x1 : 0.0f;
        selpc[base + 2] = keep ? x2 : 0.0f;
    }
}

// ---- Fallback (round-1 structure) used only if d_ws is too small ----
__global__ __launch_bounds__(256) void sor_value_kernel(
    const float* __restrict__ x, float* __restrict__ value)
{
    __shared__ float4 pts[K_PTS];
    const int b = blockIdx.y;
    const float* xb = x + (size_t)b * K_PTS * 3;
    for (int p = threadIdx.x; p < K_PTS; p += 256) {
        float a0 = xb[p * 3 + 0];
        float a1 = xb[p * 3 + 1];
        float a2 = xb[p * 3 + 2];
        pts[p] = make_float4(a0, a1, a2, a0 * a0 + a1 * a1 + a2 * a2);
    }
    __syncthreads();
    const int i = blockIdx.x * 256 + threadIdx.x;
    const float4 pi = pts[i];
    float m0 = BIGF, m1 = BIGF, m2 = BIGF;
    #pragma unroll 8
    for (int j = 0; j < K_PTS; ++j) {
        float4 pj = pts[j];
        float dot = pi.x * pj.x + pi.y * pj.y + pi.z * pj.z;
        float d = (pi.w - 2.0f * dot) + pj.w;
        insert3(d, m0, m1, m2);
    }
    value[b * K_PTS + i] = 0.5f * (m1 + m2);
}

extern "C" void kernel_launch(void* const* d_in, const int* in_sizes, int n_in,
                              void* d_out, int out_size, void* d_ws, size_t ws_size,
                              hipStream_t stream)
{
    const float* x = (const float*)d_in[0];
    float* out = (float*)d_out;
    float* value = out + (size_t)B_SZ * K_PTS * 3;

    const size_t ws_needed = (size_t)B_SZ * JS * 2 * K_PTS * sizeof(float); // 8.4 MiB

    if (ws_size >= ws_needed) {
        float* ws = (float*)d_ws;
        dim3 gA((K_PTS / ICH) * JS, B_SZ);   // (64, 16) = 1024 blocks
        sor_partial2<<<gA, THR, 0, stream>>>(x, ws);
        sor_merge<<<(B_SZ * K_PTS) / 256, 256, 0, stream>>>(x, ws, value);
    } else {
        dim3 g1(K_PTS / 256, B_SZ);
        sor_value_kernel<<<g1, 256, 0, stream>>>(x, value);
    }
    sor_mask_kernel<<<B_SZ, 1024, 0, stream>>>(x, out);
}